// Round 2
// baseline (812.473 us; speedup 1.0000x reference)
//
#include <hip/hip_runtime.h>
#include <stdint.h>

typedef unsigned short u16;
typedef __attribute__((ext_vector_type(8))) short bf16x8;
typedef __attribute__((ext_vector_type(4))) float f32x4;

#define T_TOK 4096
#define D_DIM 1024
#define F_DIM 2048
#define NEXP 8
#define BM 128
#define BK 64
#define NDESC 112

struct Desc { int row_start; int nrows; int e; int pad; };

__device__ __forceinline__ u16 f2bf(float x) {
  union { float f; unsigned u; } v; v.f = x;
  unsigned r = v.u + 0x7FFFu + ((v.u >> 16) & 1u);
  return (u16)(r >> 16);
}
__device__ __forceinline__ float bf2f(u16 b) {
  union { unsigned u; float f; } v; v.u = ((unsigned)b) << 16;
  return v.f;
}

#define GLD16(g, l) __builtin_amdgcn_global_load_lds( \
    (const __attribute__((address_space(1))) unsigned int*)(const void*)(g), \
    (__attribute__((address_space(3))) unsigned int*)(void*)(l), 16, 0, 0)

// ---------------- elementwise convert f32 -> bf16 ----------------
__global__ void k_convert(const float* __restrict__ src, u16* __restrict__ dst, int n8) {
  int i = blockIdx.x * blockDim.x + threadIdx.x;
  if (i >= n8) return;
  const float4* s = (const float4*)src + (size_t)i * 2;
  float4 a = s[0], b = s[1];
  u16 o[8] = {f2bf(a.x), f2bf(a.y), f2bf(a.z), f2bf(a.w),
              f2bf(b.x), f2bf(b.y), f2bf(b.z), f2bf(b.w)};
  *(uint4*)(dst + (size_t)i * 8) = *(const uint4*)o;
}

// ---------- convert + transpose: src [R][C] f32 -> dst [C][R] bf16 ----------
__global__ void k_tconv(const float* __restrict__ src, u16* __restrict__ dst, int R, int C) {
  size_t mo = (size_t)blockIdx.z * R * C;
  src += mo; dst += mo;
  const int rb = blockIdx.x * 64, cb = blockIdx.y * 64;
  __shared__ u16 tile[64][72];
  const int tid = threadIdx.x;
  const int lr = tid >> 4, lc = (tid & 15) * 4;
  #pragma unroll
  for (int p = 0; p < 4; p++) {
    int r = p * 16 + lr;
    float4 v = *(const float4*)(src + (size_t)(rb + r) * C + cb + lc);
    tile[r][lc + 0] = f2bf(v.x); tile[r][lc + 1] = f2bf(v.y);
    tile[r][lc + 2] = f2bf(v.z); tile[r][lc + 3] = f2bf(v.w);
  }
  __syncthreads();
  #pragma unroll
  for (int it = 0; it < 2; it++) {
    int chunk = it * 256 + tid;          // 0..511
    int c = chunk >> 3, r0 = (chunk & 7) * 8;
    u16 o[8];
    #pragma unroll
    for (int i = 0; i < 8; i++) o[i] = tile[r0 + i][c];
    *(uint4*)(dst + (size_t)(cb + c) * R + rb + r0) = *(const uint4*)o;
  }
}

// ---------------- router: fp32 logits, softmax, top-2, re-softmax ----------------
__global__ void k_router(const float* __restrict__ X, const float* __restrict__ Wr,
                         int* __restrict__ tk_idx, float* __restrict__ tk_w,
                         int* __restrict__ counts) {
  const int w = threadIdx.x >> 6, lane = threadIdx.x & 63;
  const int t = blockIdx.x * 4 + w;
  float acc[8] = {0.f, 0.f, 0.f, 0.f, 0.f, 0.f, 0.f, 0.f};
  const float* xr = X + (size_t)t * D_DIM;
  for (int i = lane; i < D_DIM; i += 64) {
    float x = xr[i];
    const float4* wrp = (const float4*)(Wr + (size_t)i * 8);
    float4 w0 = wrp[0], w1 = wrp[1];
    acc[0] += x * w0.x; acc[1] += x * w0.y; acc[2] += x * w0.z; acc[3] += x * w0.w;
    acc[4] += x * w1.x; acc[5] += x * w1.y; acc[6] += x * w1.z; acc[7] += x * w1.w;
  }
  #pragma unroll
  for (int m = 32; m; m >>= 1) {
    #pragma unroll
    for (int e = 0; e < 8; e++) acc[e] += __shfl_xor(acc[e], m);
  }
  float mx = acc[0];
  #pragma unroll
  for (int e = 1; e < 8; e++) mx = fmaxf(mx, acc[e]);
  float p[8], Z = 0.f;
  #pragma unroll
  for (int e = 0; e < 8; e++) { p[e] = expf(acc[e] - mx); Z += p[e]; }
  float inv = 1.f / Z;
  #pragma unroll
  for (int e = 0; e < 8; e++) p[e] *= inv;
  int e1 = 0; float p1 = p[0];
  #pragma unroll
  for (int e = 1; e < 8; e++) if (p[e] > p1) { p1 = p[e]; e1 = e; }
  int e2 = -1; float p2 = -1.f;
  #pragma unroll
  for (int e = 0; e < 8; e++) if (e != e1 && p[e] > p2) { p2 = p[e]; e2 = e; }
  float bb = expf(p2 - p1);
  float w1v = 1.f / (1.f + bb), w2v = 1.f - w1v;
  if (lane == 0) {
    tk_idx[t * 2] = e1; tk_idx[t * 2 + 1] = e2;
    tk_w[t * 2] = w1v;  tk_w[t * 2 + 1] = w2v;
    atomicAdd(&counts[e1], 1); atomicAdd(&counts[e2], 1);
  }
}

__global__ void k_zmeta(int* m) { if (threadIdx.x < 32) m[threadIdx.x] = 0; }

// ---------------- scan + tile descriptors (single thread; tiny) ----------------
__global__ void k_scan(const int* __restrict__ counts, int* __restrict__ offsets,
                       int* __restrict__ cursors, Desc* __restrict__ descs) {
  if (threadIdx.x != 0) return;
  int off = 0, nd = 0;
  for (int e = 0; e < NEXP; e++) {
    offsets[e] = off;
    cursors[e] = 0;
    int n = counts[e];
    for (int s = 0; s < n; s += BM) {
      descs[nd].row_start = off + s;
      descs[nd].nrows = (n - s < BM) ? (n - s) : BM;
      descs[nd].e = e; nd++;
    }
    off += n;
  }
  for (int i = 0; i < 32; i++) {
    descs[nd].row_start = 2 * T_TOK + i * BM; descs[nd].nrows = BM; descs[nd].e = NEXP; nd++;
  }
  for (; nd < NDESC; nd++) descs[nd].nrows = 0;
}

// ---------------- scatter: token -> assignment slots ----------------
__global__ void k_scatter(const int* __restrict__ tk_idx, const int* __restrict__ offsets,
                          int* __restrict__ cursors, int* __restrict__ tok,
                          int* __restrict__ pos) {
  int t = blockIdx.x * 256 + threadIdx.x;
  if (t >= T_TOK) return;
  #pragma unroll
  for (int k = 0; k < 2; k++) {
    int e = tk_idx[t * 2 + k];
    int pp = atomicAdd(&cursors[e], 1);
    int a = offsets[e] + pp;
    tok[a] = t;
    pos[t * 2 + k] = a;
  }
  tok[2 * T_TOK + t] = t;   // shared-expert identity rows
}

// ---------------- GEMM1: gu[rows][4096] = [Xrows @ WgT^T | Xrows @ WuT^T] ----------------
// LDS layout: XOR-swizzled [row][slot^(row&7)] in 16B slots (T2, rule #21:
// inverse-swizzled global source + linear global_load_lds dest + swizzled read).
__global__ __launch_bounds__(256, 4) void k_gemm1(
    const u16* __restrict__ Xb, const u16* __restrict__ WgT, const u16* __restrict__ WuT,
    const u16* __restrict__ WgTs, const u16* __restrict__ WuTs,
    const int* __restrict__ tok, const Desc* __restrict__ descs, u16* __restrict__ gu) {
  __shared__ u16 As[BM * BK];
  __shared__ u16 Bs[BM * BK];
  const Desc d = descs[blockIdx.y];
  if (d.nrows <= 0) return;
  const int is_up = (int)(blockIdx.x >> 4);
  const int n0 = (int)(blockIdx.x & 15) * 128;
  const u16* BT = (d.e == NEXP) ? (is_up ? WuTs : WgTs)
                                : ((is_up ? WuT : WgT) + (size_t)d.e * F_DIM * D_DIM);
  const int tid = threadIdx.x;
  const int w = tid >> 6, lane = tid & 63;

  const u16* pA[4]; const u16* pB[4]; unsigned aoff[4];
  #pragma unroll
  for (int j = 0; j < 4; j++) {
    const int chunk = w * 4 + j;
    const int row = chunk * 8 + (lane >> 3);
    // inverse-swizzled source column: slot (lane&7) holds col (lane&7)^(row&7)
    const int col = (((lane & 7) ^ ((lane >> 3) & 7)) * 8);
    const int tr = tok[d.row_start + row];
    pA[j] = Xb + (size_t)tr * D_DIM + col;
    pB[j] = BT + (size_t)(n0 + row) * D_DIM + col;
    aoff[j] = (unsigned)chunk * 1024u;
  }

  f32x4 acc[4][4];
  #pragma unroll
  for (int m = 0; m < 4; m++)
    #pragma unroll
    for (int n = 0; n < 4; n++) acc[m][n] = (f32x4)0.f;

  const int wr = w >> 1, wc = w & 1;
  const int sw = lane & 7;
  const u16* aP = As + (wr * 64 + (lane & 15)) * BK;
  const u16* bP = Bs + (wc * 64 + (lane & 15)) * BK;
  const int slot0 = ((lane >> 4) ^ sw) * 8;
  const int slot1 = (((lane >> 4) + 4) ^ sw) * 8;

  for (int k0 = 0; k0 < D_DIM; k0 += BK) {
    #pragma unroll
    for (int j = 0; j < 4; j++) {
      GLD16(pA[j] + k0, (char*)As + aoff[j]);
      GLD16(pB[j] + k0, (char*)Bs + aoff[j]);
    }
    __syncthreads();
    #pragma unroll
    for (int ks = 0; ks < 2; ks++) {
      const int sl = ks ? slot1 : slot0;
      bf16x8 af[4], bfr[4];
      #pragma unroll
      for (int m = 0; m < 4; m++) af[m] = *(const bf16x8*)(aP + m * 16 * BK + sl);
      #pragma unroll
      for (int n = 0; n < 4; n++) bfr[n] = *(const bf16x8*)(bP + n * 16 * BK + sl);
      #pragma unroll
      for (int m = 0; m < 4; m++)
        #pragma unroll
        for (int n = 0; n < 4; n++)
          acc[m][n] = __builtin_amdgcn_mfma_f32_16x16x32_bf16(af[m], bfr[n], acc[m][n], 0, 0, 0);
    }
    __syncthreads();
  }

  const int colbase = (is_up ? F_DIM : 0) + n0 + wc * 64;
  #pragma unroll
  for (int m = 0; m < 4; m++) {
    const int rbase = wr * 64 + m * 16 + ((lane >> 4) << 2);
    #pragma unroll
    for (int n = 0; n < 4; n++) {
      const int col = colbase + n * 16 + (lane & 15);
      #pragma unroll
      for (int j = 0; j < 4; j++) {
        const int r = rbase + j;
        if (r < d.nrows)
          gu[(size_t)(d.row_start + r) * (2 * F_DIM) + col] = f2bf(acc[m][n][j]);
      }
    }
  }
}

// ---------------- SwiGLU in place: gu[:, 0:2048] = silu(g) * u ----------------
__global__ void k_swiglu(u16* __restrict__ gu) {
  const int row = blockIdx.x;
  const int f0 = threadIdx.x * 8;
  u16* base = gu + (size_t)row * (2 * F_DIM);
  uint4 gv = *(const uint4*)(base + f0);
  uint4 uv = *(const uint4*)(base + F_DIM + f0);
  const u16* g = (const u16*)&gv;
  const u16* u = (const u16*)&uv;
  u16 o[8];
  #pragma unroll
  for (int i = 0; i < 8; i++) {
    float gf = bf2f(g[i]), uf = bf2f(u[i]);
    float h = gf / (1.f + expf(-gf)) * uf;
    o[i] = f2bf(h);
  }
  *(uint4*)(base + f0) = *(const uint4*)o;
}

// ---------------- GEMM2: eout/out = H @ Wd ----------------
__global__ __launch_bounds__(256, 4) void k_gemm2(
    const u16* __restrict__ gu, const u16* __restrict__ WdT, const u16* __restrict__ WdTs,
    const Desc* __restrict__ descs, float* __restrict__ eout, float* __restrict__ out) {
  __shared__ u16 As[BM * BK];
  __shared__ u16 Bs[BM * BK];
  const Desc d = descs[blockIdx.y];
  if (d.nrows <= 0) return;
  const int n0 = (int)blockIdx.x * 128;
  const u16* BT = (d.e == NEXP) ? WdTs : (WdT + (size_t)d.e * D_DIM * F_DIM);
  const int tid = threadIdx.x;
  const int w = tid >> 6, lane = tid & 63;

  const u16* pA[4]; const u16* pB[4]; unsigned aoff[4];
  #pragma unroll
  for (int j = 0; j < 4; j++) {
    const int chunk = w * 4 + j;
    const int row = chunk * 8 + (lane >> 3);
    const int col = (((lane & 7) ^ ((lane >> 3) & 7)) * 8);
    pA[j] = gu + (size_t)(d.row_start + row) * (2 * F_DIM) + col;
    pB[j] = BT + (size_t)(n0 + row) * F_DIM + col;
    aoff[j] = (unsigned)chunk * 1024u;
  }

  f32x4 acc[4][4];
  #pragma unroll
  for (int m = 0; m < 4; m++)
    #pragma unroll
    for (int n = 0; n < 4; n++) acc[m][n] = (f32x4)0.f;

  const int wr = w >> 1, wc = w & 1;
  const int sw = lane & 7;
  const u16* aP = As + (wr * 64 + (lane & 15)) * BK;
  const u16* bP = Bs + (wc * 64 + (lane & 15)) * BK;
  const int slot0 = ((lane >> 4) ^ sw) * 8;
  const int slot1 = (((lane >> 4) + 4) ^ sw) * 8;

  for (int k0 = 0; k0 < F_DIM; k0 += BK) {
    #pragma unroll
    for (int j = 0; j < 4; j++) {
      GLD16(pA[j] + k0, (char*)As + aoff[j]);
      GLD16(pB[j] + k0, (char*)Bs + aoff[j]);
    }
    __syncthreads();
    #pragma unroll
    for (int ks = 0; ks < 2; ks++) {
      const int sl = ks ? slot1 : slot0;
      bf16x8 af[4], bfr[4];
      #pragma unroll
      for (int m = 0; m < 4; m++) af[m] = *(const bf16x8*)(aP + m * 16 * BK + sl);
      #pragma unroll
      for (int n = 0; n < 4; n++) bfr[n] = *(const bf16x8*)(bP + n * 16 * BK + sl);
      #pragma unroll
      for (int m = 0; m < 4; m++)
        #pragma unroll
        for (int n = 0; n < 4; n++)
          acc[m][n] = __builtin_amdgcn_mfma_f32_16x16x32_bf16(af[m], bfr[n], acc[m][n], 0, 0, 0);
    }
    __syncthreads();
  }

  #pragma unroll
  for (int m = 0; m < 4; m++) {
    const int rbase = wr * 64 + m * 16 + ((lane >> 4) << 2);
    #pragma unroll
    for (int n = 0; n < 4; n++) {
      const int col = n0 + wc * 64 + n * 16 + (lane & 15);
      #pragma unroll
      for (int j = 0; j < 4; j++) {
        const int r = rbase + j;
        if (r < d.nrows) {
          const int grow = d.row_start + r;
          float v = acc[m][n][j];
          if (d.e == NEXP) out[(size_t)(grow - 2 * T_TOK) * D_DIM + col] = v;
          else             eout[(size_t)grow * D_DIM + col] = v;
        }
      }
    }
  }
}

// ---------------- combine: out[t] += w0*eout[p0] + w1*eout[p1] ----------------
__global__ void k_combine(const float* __restrict__ eout, const int* __restrict__ pos,
                          const float* __restrict__ tk_w, float* __restrict__ out) {
  const int t = blockIdx.x;
  const int dc = threadIdx.x * 4;
  const int p0 = pos[t * 2], p1 = pos[t * 2 + 1];
  const float w0 = tk_w[t * 2], w1 = tk_w[t * 2 + 1];
  float* op = out + (size_t)t * D_DIM + dc;
  float4 o = *(float4*)op;
  float4 a = *(const float4*)(eout + (size_t)p0 * D_DIM + dc);
  float4 b = *(const float4*)(eout + (size_t)p1 * D_DIM + dc);
  o.x += w0 * a.x + w1 * b.x;
  o.y += w0 * a.y + w1 * b.y;
  o.z += w0 * a.z + w1 * b.z;
  o.w += w0 * a.w + w1 * b.w;
  *(float4*)op = o;
}

extern "C" void kernel_launch(void* const* d_in, const int* in_sizes, int n_in,
                              void* d_out, int out_size, void* d_ws, size_t ws_size,
                              hipStream_t stream) {
  const float* X    = (const float*)d_in[0];
  const float* Wr   = (const float*)d_in[1];
  const float* Wg_s = (const float*)d_in[2];
  const float* Wu_s = (const float*)d_in[3];
  const float* Wd_s = (const float*)d_in[4];
  const float* Wg   = (const float*)d_in[5];
  const float* Wu   = (const float*)d_in[6];
  const float* Wd   = (const float*)d_in[7];
  float* out = (float*)d_out;

  char* ws = (char*)d_ws;
  size_t o = 0;
  auto alloc = [&](size_t bytes) -> void* {
    void* p = ws + o;
    o += (bytes + 255) & ~(size_t)255;
    return p;
  };
  u16* Xb    = (u16*)alloc((size_t)T_TOK * D_DIM * 2);
  u16* WgTs  = (u16*)alloc((size_t)F_DIM * D_DIM * 2);
  u16* WuTs  = (u16*)alloc((size_t)F_DIM * D_DIM * 2);
  u16* WdTs  = (u16*)alloc((size_t)D_DIM * F_DIM * 2);
  u16* WgT   = (u16*)alloc((size_t)NEXP * F_DIM * D_DIM * 2);
  u16* WuT   = (u16*)alloc((size_t)NEXP * F_DIM * D_DIM * 2);
  u16* WdT   = (u16*)alloc((size_t)NEXP * D_DIM * F_DIM * 2);
  u16* gu    = (u16*)alloc((size_t)(3 * T_TOK) * (2 * F_DIM) * 2);
  float* eout= (float*)alloc((size_t)(2 * T_TOK) * D_DIM * 4);
  int* tk_idx= (int*)alloc((size_t)T_TOK * 2 * 4);
  float* tk_w= (float*)alloc((size_t)T_TOK * 2 * 4);
  int* pos   = (int*)alloc((size_t)T_TOK * 2 * 4);
  int* tok   = (int*)alloc((size_t)(3 * T_TOK) * 4);
  int* meta  = (int*)alloc(256);           // counts[0:8], offsets[8:16], cursors[16:24]
  Desc* descs= (Desc*)alloc(NDESC * sizeof(Desc));
  if (o > ws_size) return;  // insufficient workspace — fail loudly

  int* counts = meta, *offsets = meta + 8, *cursors = meta + 16;

  k_zmeta<<<1, 64, 0, stream>>>(meta);
  k_convert<<<(T_TOK * D_DIM / 8 + 255) / 256, 256, 0, stream>>>(X, Xb, T_TOK * D_DIM / 8);
  k_tconv<<<dim3(D_DIM / 64, F_DIM / 64, 1), 256, 0, stream>>>(Wg_s, WgTs, D_DIM, F_DIM);
  k_tconv<<<dim3(D_DIM / 64, F_DIM / 64, 1), 256, 0, stream>>>(Wu_s, WuTs, D_DIM, F_DIM);
  k_tconv<<<dim3(F_DIM / 64, D_DIM / 64, 1), 256, 0, stream>>>(Wd_s, WdTs, F_DIM, D_DIM);
  k_tconv<<<dim3(D_DIM / 64, F_DIM / 64, NEXP), 256, 0, stream>>>(Wg, WgT, D_DIM, F_DIM);
  k_tconv<<<dim3(D_DIM / 64, F_DIM / 64, NEXP), 256, 0, stream>>>(Wu, WuT, D_DIM, F_DIM);
  k_tconv<<<dim3(F_DIM / 64, D_DIM / 64, NEXP), 256, 0, stream>>>(Wd, WdT, F_DIM, D_DIM);
  k_router<<<T_TOK / 4, 256, 0, stream>>>(X, Wr, tk_idx, tk_w, counts);
  k_scan<<<1, 64, 0, stream>>>(counts, offsets, cursors, descs);
  k_scatter<<<T_TOK / 256, 256, 0, stream>>>(tk_idx, offsets, cursors, tok, pos);
  k_gemm1<<<dim3(32, NDESC), 256, 0, stream>>>(Xb, WgT, WuT, WgTs, WuTs, tok, descs, gu);
  k_swiglu<<<3 * T_TOK, 256, 0, stream>>>(gu);
  k_gemm2<<<dim3(8, NDESC), 256, 0, stream>>>(gu, WdT, WdTs, descs, eout, out);
  k_combine<<<T_TOK, 256, 0, stream>>>(eout, pos, tk_w, out);
}

// Round 3
// 466.628 us; speedup vs baseline: 1.7412x; 1.7412x over previous
//
#include <hip/hip_runtime.h>
#include <stdint.h>

typedef unsigned short u16;
typedef __attribute__((ext_vector_type(8))) short bf16x8;
typedef __attribute__((ext_vector_type(4))) float f32x4;

#define T_TOK 4096
#define D_DIM 1024
#define F_DIM 2048
#define NEXP 8
#define BM 128
#define BK 64
#define NDESC 112

struct Desc { int row_start; int nrows; int e; int pad; };

__device__ __forceinline__ u16 f2bf(float x) {
  union { float f; unsigned u; } v; v.f = x;
  unsigned r = v.u + 0x7FFFu + ((v.u >> 16) & 1u);
  return (u16)(r >> 16);
}
__device__ __forceinline__ float bf2f(u16 b) {
  union { unsigned u; float f; } v; v.u = ((unsigned)b) << 16;
  return v.f;
}

#define GLD16(g, l) __builtin_amdgcn_global_load_lds( \
    (const __attribute__((address_space(1))) unsigned int*)(const void*)(g), \
    (__attribute__((address_space(3))) unsigned int*)(void*)(l), 16, 0, 0)

// ------------- convert f32 -> bf16 (+ zero the meta block once) -------------
__global__ void k_convert(const float* __restrict__ src, u16* __restrict__ dst, int n8,
                          int* __restrict__ meta) {
  if (blockIdx.x == 0 && threadIdx.x < 32) meta[threadIdx.x] = 0;
  int i = blockIdx.x * blockDim.x + threadIdx.x;
  if (i >= n8) return;
  const float4* s = (const float4*)src + (size_t)i * 2;
  float4 a = s[0], b = s[1];
  u16 o[8] = {f2bf(a.x), f2bf(a.y), f2bf(a.z), f2bf(a.w),
              f2bf(b.x), f2bf(b.y), f2bf(b.z), f2bf(b.w)};
  *(uint4*)(dst + (size_t)i * 8) = *(const uint4*)o;
}

// ------ convert + transpose ALL weights in one launch (z picks the slice) ------
// z in [0,8): Wg[z]  (D x F); [8,16): Wu  (D x F); [16,24): Wd (F x D);
// z==24: Wg_s; z==25: Wu_s (D x F); z==26: Wd_s (F x D).
__global__ void k_tconv_all(const float* __restrict__ Wg_s, const float* __restrict__ Wu_s,
                            const float* __restrict__ Wd_s, const float* __restrict__ Wg,
                            const float* __restrict__ Wu, const float* __restrict__ Wd,
                            u16* __restrict__ WgTs, u16* __restrict__ WuTs,
                            u16* __restrict__ WdTs, u16* __restrict__ WgT,
                            u16* __restrict__ WuT, u16* __restrict__ WdT) {
  const int z = blockIdx.z;
  const float* src; u16* dst; int R, C;
  const size_t sz = (size_t)D_DIM * F_DIM;
  if (z < 8)       { src = Wg + sz * z;        dst = WgT + sz * z;        R = D_DIM; C = F_DIM; }
  else if (z < 16) { src = Wu + sz * (z - 8);  dst = WuT + sz * (z - 8);  R = D_DIM; C = F_DIM; }
  else if (z < 24) { src = Wd + sz * (z - 16); dst = WdT + sz * (z - 16); R = F_DIM; C = D_DIM; }
  else if (z == 24){ src = Wg_s; dst = WgTs; R = D_DIM; C = F_DIM; }
  else if (z == 25){ src = Wu_s; dst = WuTs; R = D_DIM; C = F_DIM; }
  else             { src = Wd_s; dst = WdTs; R = F_DIM; C = D_DIM; }
  const int rb = blockIdx.x * 64, cb = blockIdx.y * 64;
  if (rb >= R || cb >= C) return;
  __shared__ u16 tile[64][72];
  const int tid = threadIdx.x;
  const int lr = tid >> 4, lc = (tid & 15) * 4;
  #pragma unroll
  for (int p = 0; p < 4; p++) {
    int r = p * 16 + lr;
    float4 v = *(const float4*)(src + (size_t)(rb + r) * C + cb + lc);
    tile[r][lc + 0] = f2bf(v.x); tile[r][lc + 1] = f2bf(v.y);
    tile[r][lc + 2] = f2bf(v.z); tile[r][lc + 3] = f2bf(v.w);
  }
  __syncthreads();
  #pragma unroll
  for (int it = 0; it < 2; it++) {
    int chunk = it * 256 + tid;          // 0..511
    int c = chunk >> 3, r0 = (chunk & 7) * 8;
    u16 o[8];
    #pragma unroll
    for (int i = 0; i < 8; i++) o[i] = tile[r0 + i][c];
    *(uint4*)(dst + (size_t)(cb + c) * R + rb + r0) = *(const uint4*)o;
  }
}

// ---------------- router: fp32 logits, softmax, top-2, re-softmax ----------------
__global__ void k_router(const float* __restrict__ X, const float* __restrict__ Wr,
                         int* __restrict__ tk_idx, float* __restrict__ tk_w,
                         int* __restrict__ counts) {
  const int w = threadIdx.x >> 6, lane = threadIdx.x & 63;
  const int t = blockIdx.x * 4 + w;
  float acc[8] = {0.f, 0.f, 0.f, 0.f, 0.f, 0.f, 0.f, 0.f};
  const float* xr = X + (size_t)t * D_DIM;
  for (int i = lane; i < D_DIM; i += 64) {
    float x = xr[i];
    const float4* wrp = (const float4*)(Wr + (size_t)i * 8);
    float4 w0 = wrp[0], w1 = wrp[1];
    acc[0] += x * w0.x; acc[1] += x * w0.y; acc[2] += x * w0.z; acc[3] += x * w0.w;
    acc[4] += x * w1.x; acc[5] += x * w1.y; acc[6] += x * w1.z; acc[7] += x * w1.w;
  }
  #pragma unroll
  for (int m = 32; m; m >>= 1) {
    #pragma unroll
    for (int e = 0; e < 8; e++) acc[e] += __shfl_xor(acc[e], m);
  }
  float mx = acc[0];
  #pragma unroll
  for (int e = 1; e < 8; e++) mx = fmaxf(mx, acc[e]);
  float p[8], Z = 0.f;
  #pragma unroll
  for (int e = 0; e < 8; e++) { p[e] = expf(acc[e] - mx); Z += p[e]; }
  float inv = 1.f / Z;
  #pragma unroll
  for (int e = 0; e < 8; e++) p[e] *= inv;
  int e1 = 0; float p1 = p[0];
  #pragma unroll
  for (int e = 1; e < 8; e++) if (p[e] > p1) { p1 = p[e]; e1 = e; }
  int e2 = -1; float p2 = -1.f;
  #pragma unroll
  for (int e = 0; e < 8; e++) if (e != e1 && p[e] > p2) { p2 = p[e]; e2 = e; }
  float bb = expf(p2 - p1);
  float w1v = 1.f / (1.f + bb), w2v = 1.f - w1v;
  if (lane == 0) {
    tk_idx[t * 2] = e1; tk_idx[t * 2 + 1] = e2;
    tk_w[t * 2] = w1v;  tk_w[t * 2 + 1] = w2v;
    atomicAdd(&counts[e1], 1); atomicAdd(&counts[e2], 1);
  }
}

// ---------------- scan + tile descriptors (single thread; tiny) ----------------
__global__ void k_scan(const int* __restrict__ counts, int* __restrict__ offsets,
                       int* __restrict__ cursors, Desc* __restrict__ descs) {
  if (threadIdx.x != 0) return;
  int off = 0, nd = 0;
  for (int e = 0; e < NEXP; e++) {
    offsets[e] = off;
    cursors[e] = 0;
    int n = counts[e];
    for (int s = 0; s < n; s += BM) {
      descs[nd].row_start = off + s;
      descs[nd].nrows = (n - s < BM) ? (n - s) : BM;
      descs[nd].e = e; nd++;
    }
    off += n;
  }
  for (int i = 0; i < 32; i++) {
    descs[nd].row_start = 2 * T_TOK + i * BM; descs[nd].nrows = BM; descs[nd].e = NEXP; nd++;
  }
  for (; nd < NDESC; nd++) descs[nd].nrows = 0;
}

// ---------------- scatter: token -> assignment slots ----------------
__global__ void k_scatter(const int* __restrict__ tk_idx, const int* __restrict__ offsets,
                          int* __restrict__ cursors, int* __restrict__ tok,
                          int* __restrict__ pos) {
  int t = blockIdx.x * 256 + threadIdx.x;
  if (t >= T_TOK) return;
  #pragma unroll
  for (int k = 0; k < 2; k++) {
    int e = tk_idx[t * 2 + k];
    int pp = atomicAdd(&cursors[e], 1);
    int a = offsets[e] + pp;
    tok[a] = t;
    pos[t * 2 + k] = a;
  }
  tok[2 * T_TOK + t] = t;   // shared-expert identity rows
}

// -------- GEMM1 fused: h[rows][2048] = silu(Xrows@Wg^T) * (Xrows@Wu^T) --------
// LDS: XOR-swizzled 16B slots (T2; inverse-swizzled global source + linear
// global_load_lds dest + swizzled ds_read — rule #21). Both Bg and Bu staged
// per block so silu(g)*u fuses in the f32 epilogue.
__global__ __launch_bounds__(256, 2) void k_gemm1(
    const u16* __restrict__ Xb, const u16* __restrict__ WgT, const u16* __restrict__ WuT,
    const u16* __restrict__ WgTs, const u16* __restrict__ WuTs,
    const int* __restrict__ tok, const Desc* __restrict__ descs, u16* __restrict__ h) {
  __shared__ u16 As[BM * BK];
  __shared__ u16 Bgs[BM * BK];
  __shared__ u16 Bus[BM * BK];
  const Desc d = descs[blockIdx.y];
  if (d.nrows <= 0) return;
  const int n0 = (int)blockIdx.x * 128;
  const u16* BTg = (d.e == NEXP) ? WgTs : (WgT + (size_t)d.e * F_DIM * D_DIM);
  const u16* BTu = (d.e == NEXP) ? WuTs : (WuT + (size_t)d.e * F_DIM * D_DIM);
  const int tid = threadIdx.x;
  const int w = tid >> 6, lane = tid & 63;

  const u16* pA[4]; const u16* pBg[4]; const u16* pBu[4]; unsigned aoff[4];
  #pragma unroll
  for (int j = 0; j < 4; j++) {
    const int chunk = w * 4 + j;
    const int row = chunk * 8 + (lane >> 3);
    // inverse-swizzled source column: slot (lane&7) holds col (lane&7)^(row&7)
    const int col = (((lane & 7) ^ ((lane >> 3) & 7)) * 8);
    const int tr = tok[d.row_start + row];
    pA[j]  = Xb  + (size_t)tr * D_DIM + col;
    pBg[j] = BTg + (size_t)(n0 + row) * D_DIM + col;
    pBu[j] = BTu + (size_t)(n0 + row) * D_DIM + col;
    aoff[j] = (unsigned)chunk * 1024u;
  }

  f32x4 ag[4][4], au[4][4];
  #pragma unroll
  for (int m = 0; m < 4; m++)
    #pragma unroll
    for (int n = 0; n < 4; n++) { ag[m][n] = (f32x4)0.f; au[m][n] = (f32x4)0.f; }

  const int wr = w >> 1, wc = w & 1;
  const int sw = lane & 7;
  const u16* aP = As  + (wr * 64 + (lane & 15)) * BK;
  const u16* gP = Bgs + (wc * 64 + (lane & 15)) * BK;
  const u16* uP = Bus + (wc * 64 + (lane & 15)) * BK;
  const int slot0 = ((lane >> 4) ^ sw) * 8;
  const int slot1 = (((lane >> 4) + 4) ^ sw) * 8;

  for (int k0 = 0; k0 < D_DIM; k0 += BK) {
    #pragma unroll
    for (int j = 0; j < 4; j++) {
      GLD16(pA[j] + k0,  (char*)As  + aoff[j]);
      GLD16(pBg[j] + k0, (char*)Bgs + aoff[j]);
      GLD16(pBu[j] + k0, (char*)Bus + aoff[j]);
    }
    __syncthreads();
    #pragma unroll
    for (int ks = 0; ks < 2; ks++) {
      const int sl = ks ? slot1 : slot0;
      bf16x8 af[4], bg[4], bu[4];
      #pragma unroll
      for (int m = 0; m < 4; m++) af[m] = *(const bf16x8*)(aP + m * 16 * BK + sl);
      #pragma unroll
      for (int n = 0; n < 4; n++) bg[n] = *(const bf16x8*)(gP + n * 16 * BK + sl);
      #pragma unroll
      for (int n = 0; n < 4; n++) bu[n] = *(const bf16x8*)(uP + n * 16 * BK + sl);
      #pragma unroll
      for (int m = 0; m < 4; m++)
        #pragma unroll
        for (int n = 0; n < 4; n++) {
          ag[m][n] = __builtin_amdgcn_mfma_f32_16x16x32_bf16(af[m], bg[n], ag[m][n], 0, 0, 0);
          au[m][n] = __builtin_amdgcn_mfma_f32_16x16x32_bf16(af[m], bu[n], au[m][n], 0, 0, 0);
        }
    }
    __syncthreads();
  }

  const int colbase = n0 + wc * 64;
  #pragma unroll
  for (int m = 0; m < 4; m++) {
    const int rbase = wr * 64 + m * 16 + ((lane >> 4) << 2);
    #pragma unroll
    for (int n = 0; n < 4; n++) {
      const int col = colbase + n * 16 + (lane & 15);
      #pragma unroll
      for (int j = 0; j < 4; j++) {
        const int r = rbase + j;
        if (r < d.nrows) {
          float gf = ag[m][n][j], uf = au[m][n][j];
          float hv = gf / (1.f + expf(-gf)) * uf;
          h[(size_t)(d.row_start + r) * F_DIM + col] = f2bf(hv);
        }
      }
    }
  }
}

// ---------------- GEMM2: eout/out = H @ Wd ----------------
__global__ __launch_bounds__(256, 2) void k_gemm2(
    const u16* __restrict__ h, const u16* __restrict__ WdT, const u16* __restrict__ WdTs,
    const Desc* __restrict__ descs, float* __restrict__ eout, float* __restrict__ out) {
  __shared__ u16 As[BM * BK];
  __shared__ u16 Bs[BM * BK];
  const Desc d = descs[blockIdx.y];
  if (d.nrows <= 0) return;
  const int n0 = (int)blockIdx.x * 128;
  const u16* BT = (d.e == NEXP) ? WdTs : (WdT + (size_t)d.e * D_DIM * F_DIM);
  const int tid = threadIdx.x;
  const int w = tid >> 6, lane = tid & 63;

  const u16* pA[4]; const u16* pB[4]; unsigned aoff[4];
  #pragma unroll
  for (int j = 0; j < 4; j++) {
    const int chunk = w * 4 + j;
    const int row = chunk * 8 + (lane >> 3);
    const int col = (((lane & 7) ^ ((lane >> 3) & 7)) * 8);
    pA[j] = h + (size_t)(d.row_start + row) * F_DIM + col;
    pB[j] = BT + (size_t)(n0 + row) * F_DIM + col;
    aoff[j] = (unsigned)chunk * 1024u;
  }

  f32x4 acc[4][4];
  #pragma unroll
  for (int m = 0; m < 4; m++)
    #pragma unroll
    for (int n = 0; n < 4; n++) acc[m][n] = (f32x4)0.f;

  const int wr = w >> 1, wc = w & 1;
  const int sw = lane & 7;
  const u16* aP = As + (wr * 64 + (lane & 15)) * BK;
  const u16* bP = Bs + (wc * 64 + (lane & 15)) * BK;
  const int slot0 = ((lane >> 4) ^ sw) * 8;
  const int slot1 = (((lane >> 4) + 4) ^ sw) * 8;

  for (int k0 = 0; k0 < F_DIM; k0 += BK) {
    #pragma unroll
    for (int j = 0; j < 4; j++) {
      GLD16(pA[j] + k0, (char*)As + aoff[j]);
      GLD16(pB[j] + k0, (char*)Bs + aoff[j]);
    }
    __syncthreads();
    #pragma unroll
    for (int ks = 0; ks < 2; ks++) {
      const int sl = ks ? slot1 : slot0;
      bf16x8 af[4], bfr[4];
      #pragma unroll
      for (int m = 0; m < 4; m++) af[m] = *(const bf16x8*)(aP + m * 16 * BK + sl);
      #pragma unroll
      for (int n = 0; n < 4; n++) bfr[n] = *(const bf16x8*)(bP + n * 16 * BK + sl);
      #pragma unroll
      for (int m = 0; m < 4; m++)
        #pragma unroll
        for (int n = 0; n < 4; n++)
          acc[m][n] = __builtin_amdgcn_mfma_f32_16x16x32_bf16(af[m], bfr[n], acc[m][n], 0, 0, 0);
    }
    __syncthreads();
  }

  #pragma unroll
  for (int m = 0; m < 4; m++) {
    const int rbase = wr * 64 + m * 16 + ((lane >> 4) << 2);
    #pragma unroll
    for (int n = 0; n < 4; n++) {
      const int col = n0 + wc * 64 + n * 16 + (lane & 15);
      #pragma unroll
      for (int j = 0; j < 4; j++) {
        const int r = rbase + j;
        if (r < d.nrows) {
          const int grow = d.row_start + r;
          float v = acc[m][n][j];
          if (d.e == NEXP) out[(size_t)(grow - 2 * T_TOK) * D_DIM + col] = v;
          else             eout[(size_t)grow * D_DIM + col] = v;
        }
      }
    }
  }
}

// ---------------- combine: out[t] += w0*eout[p0] + w1*eout[p1] ----------------
__global__ void k_combine(const float* __restrict__ eout, const int* __restrict__ pos,
                          const float* __restrict__ tk_w, float* __restrict__ out) {
  const int t = blockIdx.x;
  const int dc = threadIdx.x * 4;
  const int p0 = pos[t * 2], p1 = pos[t * 2 + 1];
  const float w0 = tk_w[t * 2], w1 = tk_w[t * 2 + 1];
  float* op = out + (size_t)t * D_DIM + dc;
  float4 o = *(float4*)op;
  float4 a = *(const float4*)(eout + (size_t)p0 * D_DIM + dc);
  float4 b = *(const float4*)(eout + (size_t)p1 * D_DIM + dc);
  o.x += w0 * a.x + w1 * b.x;
  o.y += w0 * a.y + w1 * b.y;
  o.z += w0 * a.z + w1 * b.z;
  o.w += w0 * a.w + w1 * b.w;
  *(float4*)op = o;
}

extern "C" void kernel_launch(void* const* d_in, const int* in_sizes, int n_in,
                              void* d_out, int out_size, void* d_ws, size_t ws_size,
                              hipStream_t stream) {
  const float* X    = (const float*)d_in[0];
  const float* Wr   = (const float*)d_in[1];
  const float* Wg_s = (const float*)d_in[2];
  const float* Wu_s = (const float*)d_in[3];
  const float* Wd_s = (const float*)d_in[4];
  const float* Wg   = (const float*)d_in[5];
  const float* Wu   = (const float*)d_in[6];
  const float* Wd   = (const float*)d_in[7];
  float* out = (float*)d_out;

  char* ws = (char*)d_ws;
  size_t o = 0;
  auto alloc = [&](size_t bytes) -> void* {
    void* p = ws + o;
    o += (bytes + 255) & ~(size_t)255;
    return p;
  };
  u16* Xb    = (u16*)alloc((size_t)T_TOK * D_DIM * 2);
  u16* WgTs  = (u16*)alloc((size_t)F_DIM * D_DIM * 2);
  u16* WuTs  = (u16*)alloc((size_t)F_DIM * D_DIM * 2);
  u16* WdTs  = (u16*)alloc((size_t)D_DIM * F_DIM * 2);
  u16* WgT   = (u16*)alloc((size_t)NEXP * F_DIM * D_DIM * 2);
  u16* WuT   = (u16*)alloc((size_t)NEXP * F_DIM * D_DIM * 2);
  u16* WdT   = (u16*)alloc((size_t)NEXP * D_DIM * F_DIM * 2);
  u16* h     = (u16*)alloc((size_t)(3 * T_TOK) * F_DIM * 2);
  float* eout= (float*)alloc((size_t)(2 * T_TOK) * D_DIM * 4);
  int* tk_idx= (int*)alloc((size_t)T_TOK * 2 * 4);
  float* tk_w= (float*)alloc((size_t)T_TOK * 2 * 4);
  int* pos   = (int*)alloc((size_t)T_TOK * 2 * 4);
  int* tok   = (int*)alloc((size_t)(3 * T_TOK) * 4);
  int* meta  = (int*)alloc(256);           // counts[0:8], offsets[8:16], cursors[16:24]
  Desc* descs= (Desc*)alloc(NDESC * sizeof(Desc));
  if (o > ws_size) return;  // insufficient workspace — fail loudly

  int* counts = meta, *offsets = meta + 8, *cursors = meta + 16;

  k_convert<<<(T_TOK * D_DIM / 8 + 255) / 256, 256, 0, stream>>>(X, Xb, T_TOK * D_DIM / 8, meta);
  k_tconv_all<<<dim3(32, 32, 27), 256, 0, stream>>>(Wg_s, Wu_s, Wd_s, Wg, Wu, Wd,
                                                    WgTs, WuTs, WdTs, WgT, WuT, WdT);
  k_router<<<T_TOK / 4, 256, 0, stream>>>(X, Wr, tk_idx, tk_w, counts);
  k_scan<<<1, 64, 0, stream>>>(counts, offsets, cursors, descs);
  k_scatter<<<T_TOK / 256, 256, 0, stream>>>(tk_idx, offsets, cursors, tok, pos);
  k_gemm1<<<dim3(16, NDESC), 256, 0, stream>>>(Xb, WgT, WuT, WgTs, WuTs, tok, descs, h);
  k_gemm2<<<dim3(8, NDESC), 256, 0, stream>>>(h, WdT, WdTs, descs, eout, out);
  k_combine<<<T_TOK, 256, 0, stream>>>(eout, pos, tk_w, out);
}

// Round 4
// 441.645 us; speedup vs baseline: 1.8397x; 1.0566x over previous
//
#include <hip/hip_runtime.h>
#include <stdint.h>

typedef unsigned short u16;
typedef __attribute__((ext_vector_type(8))) short bf16x8;
typedef __attribute__((ext_vector_type(4))) float f32x4;

#define T_TOK 4096
#define D_DIM 1024
#define F_DIM 2048
#define NEXP 8
#define BK 64
#define NDESC 64          // 256-row tiles: routed <= 39, shared 16

struct Desc { int row_start; int nrows; int e; int pad; };

__device__ __forceinline__ u16 f2bf(float x) {
  union { float f; unsigned u; } v; v.f = x;
  unsigned r = v.u + 0x7FFFu + ((v.u >> 16) & 1u);
  return (u16)(r >> 16);
}
__device__ __forceinline__ float bf2f(u16 b) {
  union { unsigned u; float f; } v; v.u = ((unsigned)b) << 16;
  return v.f;
}

#define GLD16(g, l) __builtin_amdgcn_global_load_lds( \
    (const __attribute__((address_space(1))) unsigned int*)(const void*)(g), \
    (__attribute__((address_space(3))) unsigned int*)(void*)(l), 16, 0, 0)

#define VMCNT0() asm volatile("s_waitcnt vmcnt(0)" ::: "memory")
#define SBAR()   __builtin_amdgcn_s_barrier()

// ------------- convert f32 -> bf16 (+ zero the meta block once) -------------
__global__ void k_convert(const float* __restrict__ src, u16* __restrict__ dst, int n8,
                          int* __restrict__ meta) {
  if (blockIdx.x == 0 && threadIdx.x < 32) meta[threadIdx.x] = 0;
  int i = blockIdx.x * blockDim.x + threadIdx.x;
  if (i >= n8) return;
  const float4* s = (const float4*)src + (size_t)i * 2;
  float4 a = s[0], b = s[1];
  u16 o[8] = {f2bf(a.x), f2bf(a.y), f2bf(a.z), f2bf(a.w),
              f2bf(b.x), f2bf(b.y), f2bf(b.z), f2bf(b.w)};
  *(uint4*)(dst + (size_t)i * 8) = *(const uint4*)o;
}

// ------ convert + transpose ALL weights; grid (16,32,27), zero empty blocks ------
__global__ void k_tconv_all(const float* __restrict__ Wg_s, const float* __restrict__ Wu_s,
                            const float* __restrict__ Wd_s, const float* __restrict__ Wg,
                            const float* __restrict__ Wu, const float* __restrict__ Wd,
                            u16* __restrict__ WgTs, u16* __restrict__ WuTs,
                            u16* __restrict__ WdTs, u16* __restrict__ WgT,
                            u16* __restrict__ WuT, u16* __restrict__ WdT) {
  const int z = blockIdx.z;
  const float* src; u16* dst; int R, C;
  const size_t sz = (size_t)D_DIM * F_DIM;
  if (z < 8)       { src = Wg + sz * z;        dst = WgT + sz * z;        R = D_DIM; C = F_DIM; }
  else if (z < 16) { src = Wu + sz * (z - 8);  dst = WuT + sz * (z - 8);  R = D_DIM; C = F_DIM; }
  else if (z < 24) { src = Wd + sz * (z - 16); dst = WdT + sz * (z - 16); R = F_DIM; C = D_DIM; }
  else if (z == 24){ src = Wg_s; dst = WgTs; R = D_DIM; C = F_DIM; }
  else if (z == 25){ src = Wu_s; dst = WuTs; R = D_DIM; C = F_DIM; }
  else             { src = Wd_s; dst = WdTs; R = F_DIM; C = D_DIM; }
  const bool tall = (R > C);
  const int rb = (tall ? blockIdx.y : blockIdx.x) * 64;
  const int cb = (tall ? blockIdx.x : blockIdx.y) * 64;
  __shared__ u16 tile[64][72];
  const int tid = threadIdx.x;
  const int lr = tid >> 4, lc = (tid & 15) * 4;
  #pragma unroll
  for (int p = 0; p < 4; p++) {
    int r = p * 16 + lr;
    float4 v = *(const float4*)(src + (size_t)(rb + r) * C + cb + lc);
    tile[r][lc + 0] = f2bf(v.x); tile[r][lc + 1] = f2bf(v.y);
    tile[r][lc + 2] = f2bf(v.z); tile[r][lc + 3] = f2bf(v.w);
  }
  __syncthreads();
  #pragma unroll
  for (int it = 0; it < 2; it++) {
    int chunk = it * 256 + tid;
    int c = chunk >> 3, r0 = (chunk & 7) * 8;
    u16 o[8];
    #pragma unroll
    for (int i = 0; i < 8; i++) o[i] = tile[r0 + i][c];
    *(uint4*)(dst + (size_t)(cb + c) * R + rb + r0) = *(const uint4*)o;
  }
}

// ---------------- router: fp32 logits, softmax, top-2, re-softmax ----------------
__global__ void k_router(const float* __restrict__ X, const float* __restrict__ Wr,
                         int* __restrict__ tk_idx, float* __restrict__ tk_w,
                         int* __restrict__ counts) {
  const int w = threadIdx.x >> 6, lane = threadIdx.x & 63;
  const int t = blockIdx.x * 4 + w;
  float acc[8] = {0.f, 0.f, 0.f, 0.f, 0.f, 0.f, 0.f, 0.f};
  const float* xr = X + (size_t)t * D_DIM;
  #pragma unroll
  for (int it = 0; it < 4; it++) {
    const int i0 = it * 256 + lane * 4;
    float4 xv = *(const float4*)(xr + i0);
    float xs[4] = {xv.x, xv.y, xv.z, xv.w};
    #pragma unroll
    for (int j = 0; j < 4; j++) {
      const float4* wrp = (const float4*)(Wr + (size_t)(i0 + j) * 8);
      float4 w0 = wrp[0], w1 = wrp[1];
      float x = xs[j];
      acc[0] += x * w0.x; acc[1] += x * w0.y; acc[2] += x * w0.z; acc[3] += x * w0.w;
      acc[4] += x * w1.x; acc[5] += x * w1.y; acc[6] += x * w1.z; acc[7] += x * w1.w;
    }
  }
  #pragma unroll
  for (int m = 32; m; m >>= 1) {
    #pragma unroll
    for (int e = 0; e < 8; e++) acc[e] += __shfl_xor(acc[e], m);
  }
  float mx = acc[0];
  #pragma unroll
  for (int e = 1; e < 8; e++) mx = fmaxf(mx, acc[e]);
  float p[8], Z = 0.f;
  #pragma unroll
  for (int e = 0; e < 8; e++) { p[e] = expf(acc[e] - mx); Z += p[e]; }
  float inv = 1.f / Z;
  #pragma unroll
  for (int e = 0; e < 8; e++) p[e] *= inv;
  int e1 = 0; float p1 = p[0];
  #pragma unroll
  for (int e = 1; e < 8; e++) if (p[e] > p1) { p1 = p[e]; e1 = e; }
  int e2 = -1; float p2 = -1.f;
  #pragma unroll
  for (int e = 0; e < 8; e++) if (e != e1 && p[e] > p2) { p2 = p[e]; e2 = e; }
  float bb = expf(p2 - p1);
  float w1v = 1.f / (1.f + bb), w2v = 1.f - w1v;
  if (lane == 0) {
    tk_idx[t * 2] = e1; tk_idx[t * 2 + 1] = e2;
    tk_w[t * 2] = w1v;  tk_w[t * 2 + 1] = w2v;
    atomicAdd(&counts[e1], 1); atomicAdd(&counts[e2], 1);
  }
}

// ------------- scan + 256-row tile descriptors (64 lanes, parallel) -------------
__global__ void k_scan(const int* __restrict__ counts, int* __restrict__ offsets,
                       int* __restrict__ cursors, Desc* __restrict__ descs) {
  const int lane = threadIdx.x;
  int cnt[8], off[9], tst[9];
  off[0] = 0; tst[0] = 0;
  #pragma unroll
  for (int e = 0; e < 8; e++) {
    cnt[e] = counts[e];
    off[e + 1] = off[e] + cnt[e];
    tst[e + 1] = tst[e] + ((cnt[e] + 255) >> 8);
  }
  if (lane < 8) { offsets[lane] = off[lane]; cursors[lane] = 0; }
  const int tr = tst[8];
  for (int i = lane; i < NDESC; i += 64) {
    Desc dd; dd.nrows = 0; dd.row_start = 0; dd.e = 0; dd.pad = 0;
    if (i < tr) {
      int e = 0;
      #pragma unroll
      for (int q = 0; q < 7; q++) if (i >= tst[q + 1]) e = q + 1;
      int s = (i - tst[e]) << 8;
      dd.row_start = off[e] + s;
      int rem = cnt[e] - s;
      dd.nrows = rem < 256 ? rem : 256;
      dd.e = e;
    } else if (i < tr + T_TOK / 256) {
      int j = i - tr;
      dd.row_start = 2 * T_TOK + j * 256; dd.nrows = 256; dd.e = NEXP;
    }
    descs[i] = dd;
  }
}

// ---------------- scatter: token -> assignment slots ----------------
__global__ void k_scatter(const int* __restrict__ tk_idx, const int* __restrict__ offsets,
                          int* __restrict__ cursors, int* __restrict__ tok,
                          int* __restrict__ pos) {
  int t = blockIdx.x * 256 + threadIdx.x;
  if (t >= T_TOK) return;
  #pragma unroll
  for (int k = 0; k < 2; k++) {
    int e = tk_idx[t * 2 + k];
    int pp = atomicAdd(&cursors[e], 1);
    int a = offsets[e] + pp;
    tok[a] = t;
    pos[t * 2 + k] = a;
  }
  tok[2 * T_TOK + t] = t;
}

// ======== GEMM1 fused, 8-phase: h = silu(X@Wg^T) * (X@Wu^T), BM=256 BN=128 ========
// 512 thr = 8 waves (4M x 2N). LDS 128KB: 2 bufs x { A[256][64] | Bg[128][64] | Bu[128][64] }.
// XOR-swizzled 16B slots (inverse-swizzled global source, linear gld dest, swizzled read).
// Per K-tile: 4 phases x {ds_read quadrant; (stage next tile, ph0 only); s_barrier;
// setprio(1); 16 MFMA; setprio(0); s_barrier}; vmcnt(0) only before phase-3's final barrier.
__global__ __launch_bounds__(512) void k_gemm1(
    const u16* __restrict__ Xb, const u16* __restrict__ WgT, const u16* __restrict__ WuT,
    const u16* __restrict__ WgTs, const u16* __restrict__ WuTs,
    const int* __restrict__ tok, const Desc* __restrict__ descs, u16* __restrict__ h) {
  __shared__ u16 lds[65536];          // 128 KB
  const Desc d = descs[blockIdx.y];
  if (d.nrows <= 0) return;
  const int n0 = (int)blockIdx.x * 128;
  const u16* BTg = (d.e == NEXP) ? WgTs : (WgT + (size_t)d.e * F_DIM * D_DIM);
  const u16* BTu = (d.e == NEXP) ? WuTs : (WuT + (size_t)d.e * F_DIM * D_DIM);
  const int tid = threadIdx.x;
  const int w = tid >> 6, lane = tid & 63;
  const int wr = w >> 1, wc = w & 1;
  char* ldsc = (char*)lds;

  // staging sources (inverse-swizzled column so swizzled read sees linear cols)
  const int srow = tid >> 3;                       // 0..63
  const int scol = ((tid & 7) ^ ((tid >> 3) & 7)) * 8;
  const u16* gA[4]; const u16* gBg[2]; const u16* gBu[2];
  #pragma unroll
  for (int c = 0; c < 4; c++)
    gA[c] = Xb + (size_t)tok[d.row_start + c * 64 + srow] * D_DIM + scol;
  #pragma unroll
  for (int c = 0; c < 2; c++) {
    gBg[c] = BTg + (size_t)(n0 + c * 64 + srow) * D_DIM + scol;
    gBu[c] = BTu + (size_t)(n0 + c * 64 + srow) * D_DIM + scol;
  }
  const int sdst = tid * 16;

  // ds_read bases (byte offsets in buffer 0)
  const int sw = lane & 7, kq = lane >> 4;
  const int arow = wr * 64 + (lane & 15);
  const int aoff0 = arow * 128 + ((kq ^ sw) * 16);
  const int aoff1 = arow * 128 + (((4 + kq) ^ sw) * 16);
  const int brow = wc * 64 + (lane & 15);
  const int goff0 = 32768 + brow * 128 + ((kq ^ sw) * 16);
  const int goff1 = 32768 + brow * 128 + (((4 + kq) ^ sw) * 16);

  f32x4 ag[4][4], au[4][4];
  #pragma unroll
  for (int m = 0; m < 4; m++)
    #pragma unroll
    for (int n = 0; n < 4; n++) { ag[m][n] = (f32x4)0.f; au[m][n] = (f32x4)0.f; }

  // prologue: stage tile 0 -> buf0
  #pragma unroll
  for (int c = 0; c < 4; c++) GLD16(gA[c], ldsc + c * 8192 + sdst);
  #pragma unroll
  for (int c = 0; c < 2; c++) GLD16(gBg[c], ldsc + 32768 + c * 8192 + sdst);
  #pragma unroll
  for (int c = 0; c < 2; c++) GLD16(gBu[c], ldsc + 49152 + c * 8192 + sdst);
  VMCNT0();
  SBAR();

  const int NT1 = D_DIM / BK;   // 16
  for (int t = 0; t < NT1; ++t) {
    const int cb = (t & 1) << 16;
    const int sb = ((t + 1) & 1) << 16;
    const bool more = (t + 1 < NT1);
    bf16x8 af[4], bf[4];
    // ---- phase 0: a(kk0), bg(kk0); stage tile t+1; MFMA g/kk0
    #pragma unroll
    for (int m = 0; m < 4; m++) af[m] = *(const bf16x8*)(ldsc + cb + aoff0 + m * 2048);
    #pragma unroll
    for (int n = 0; n < 4; n++) bf[n] = *(const bf16x8*)(ldsc + cb + goff0 + n * 2048);
    if (more) {
      #pragma unroll
      for (int c = 0; c < 4; c++) { gA[c] += BK; GLD16(gA[c], ldsc + sb + c * 8192 + sdst); }
      #pragma unroll
      for (int c = 0; c < 2; c++) { gBg[c] += BK; GLD16(gBg[c], ldsc + sb + 32768 + c * 8192 + sdst); }
      #pragma unroll
      for (int c = 0; c < 2; c++) { gBu[c] += BK; GLD16(gBu[c], ldsc + sb + 49152 + c * 8192 + sdst); }
    }
    SBAR();
    __builtin_amdgcn_s_setprio(1);
    #pragma unroll
    for (int m = 0; m < 4; m++)
      #pragma unroll
      for (int n = 0; n < 4; n++)
        ag[m][n] = __builtin_amdgcn_mfma_f32_16x16x32_bf16(af[m], bf[n], ag[m][n], 0, 0, 0);
    __builtin_amdgcn_s_setprio(0);
    SBAR();
    // ---- phase 1: bu(kk0); MFMA u/kk0 (af reused)
    #pragma unroll
    for (int n = 0; n < 4; n++) bf[n] = *(const bf16x8*)(ldsc + cb + goff0 + 16384 + n * 2048);
    SBAR();
    __builtin_amdgcn_s_setprio(1);
    #pragma unroll
    for (int m = 0; m < 4; m++)
      #pragma unroll
      for (int n = 0; n < 4; n++)
        au[m][n] = __builtin_amdgcn_mfma_f32_16x16x32_bf16(af[m], bf[n], au[m][n], 0, 0, 0);
    __builtin_amdgcn_s_setprio(0);
    SBAR();
    // ---- phase 2: a(kk1), bg(kk1); MFMA g/kk1
    #pragma unroll
    for (int m = 0; m < 4; m++) af[m] = *(const bf16x8*)(ldsc + cb + aoff1 + m * 2048);
    #pragma unroll
    for (int n = 0; n < 4; n++) bf[n] = *(const bf16x8*)(ldsc + cb + goff1 + n * 2048);
    SBAR();
    __builtin_amdgcn_s_setprio(1);
    #pragma unroll
    for (int m = 0; m < 4; m++)
      #pragma unroll
      for (int n = 0; n < 4; n++)
        ag[m][n] = __builtin_amdgcn_mfma_f32_16x16x32_bf16(af[m], bf[n], ag[m][n], 0, 0, 0);
    __builtin_amdgcn_s_setprio(0);
    SBAR();
    // ---- phase 3: bu(kk1); MFMA u/kk1; drain stage; final barrier
    #pragma unroll
    for (int n = 0; n < 4; n++) bf[n] = *(const bf16x8*)(ldsc + cb + goff1 + 16384 + n * 2048);
    SBAR();
    __builtin_amdgcn_s_setprio(1);
    #pragma unroll
    for (int m = 0; m < 4; m++)
      #pragma unroll
      for (int n = 0; n < 4; n++)
        au[m][n] = __builtin_amdgcn_mfma_f32_16x16x32_bf16(af[m], bf[n], au[m][n], 0, 0, 0);
    __builtin_amdgcn_s_setprio(0);
    if (more) { VMCNT0(); SBAR(); }
  }

  // epilogue: silu(g)*u, masked bf16 store
  #pragma unroll
  for (int m = 0; m < 4; m++) {
    const int rbase = wr * 64 + m * 16 + ((lane >> 4) << 2);
    #pragma unroll
    for (int n = 0; n < 4; n++) {
      const int col = n0 + wc * 64 + n * 16 + (lane & 15);
      #pragma unroll
      for (int j = 0; j < 4; j++) {
        const int r = rbase + j;
        if (r < d.nrows) {
          float gf = ag[m][n][j], uf = au[m][n][j];
          float hv = gf / (1.f + expf(-gf)) * uf;
          h[(size_t)(d.row_start + r) * F_DIM + col] = f2bf(hv);
        }
      }
    }
  }
}

// ======== GEMM2, 8-phase: eout/out = H @ Wd, BM=256 BN=256 ========
__global__ __launch_bounds__(512) void k_gemm2(
    const u16* __restrict__ h, const u16* __restrict__ WdT, const u16* __restrict__ WdTs,
    const Desc* __restrict__ descs, float* __restrict__ eout, float* __restrict__ out) {
  __shared__ u16 lds[65536];
  const Desc d = descs[blockIdx.y];
  if (d.nrows <= 0) return;
  const int n0 = (int)blockIdx.x * 256;
  const u16* BT = (d.e == NEXP) ? WdTs : (WdT + (size_t)d.e * D_DIM * F_DIM);
  const int tid = threadIdx.x;
  const int w = tid >> 6, lane = tid & 63;
  const int wr = w >> 1, wc = w & 1;
  char* ldsc = (char*)lds;

  const int srow = tid >> 3;
  const int scol = ((tid & 7) ^ ((tid >> 3) & 7)) * 8;
  const u16* gA[4]; const u16* gB[4];
  #pragma unroll
  for (int c = 0; c < 4; c++) {
    gA[c] = h + (size_t)(d.row_start + c * 64 + srow) * F_DIM + scol;
    gB[c] = BT + (size_t)(n0 + c * 64 + srow) * F_DIM + scol;
  }
  const int sdst = tid * 16;

  const int sw = lane & 7, kq = lane >> 4;
  const int arow = wr * 64 + (lane & 15);
  const int aoff0 = arow * 128 + ((kq ^ sw) * 16);
  const int aoff1 = arow * 128 + (((4 + kq) ^ sw) * 16);
  const int brow = wc * 128 + (lane & 15);
  const int boff0 = 32768 + brow * 128 + ((kq ^ sw) * 16);
  const int boff1 = 32768 + brow * 128 + (((4 + kq) ^ sw) * 16);

  f32x4 acc[4][8];
  #pragma unroll
  for (int m = 0; m < 4; m++)
    #pragma unroll
    for (int n = 0; n < 8; n++) acc[m][n] = (f32x4)0.f;

  #pragma unroll
  for (int c = 0; c < 4; c++) {
    GLD16(gA[c], ldsc + c * 8192 + sdst);
    GLD16(gB[c], ldsc + 32768 + c * 8192 + sdst);
  }
  VMCNT0();
  SBAR();

  const int NT2 = F_DIM / BK;   // 32
  for (int t = 0; t < NT2; ++t) {
    const int cb = (t & 1) << 16;
    const int sb = ((t + 1) & 1) << 16;
    const bool more = (t + 1 < NT2);
    bf16x8 af[4], bf[4];
    // ---- phase 0: a(kk0), b(kk0,n0-3); stage; MFMA
    #pragma unroll
    for (int m = 0; m < 4; m++) af[m] = *(const bf16x8*)(ldsc + cb + aoff0 + m * 2048);
    #pragma unroll
    for (int n = 0; n < 4; n++) bf[n] = *(const bf16x8*)(ldsc + cb + boff0 + n * 2048);
    if (more) {
      #pragma unroll
      for (int c = 0; c < 4; c++) {
        gA[c] += BK; GLD16(gA[c], ldsc + sb + c * 8192 + sdst);
        gB[c] += BK; GLD16(gB[c], ldsc + sb + 32768 + c * 8192 + sdst);
      }
    }
    SBAR();
    __builtin_amdgcn_s_setprio(1);
    #pragma unroll
    for (int m = 0; m < 4; m++)
      #pragma unroll
      for (int n = 0; n < 4; n++)
        acc[m][n] = __builtin_amdgcn_mfma_f32_16x16x32_bf16(af[m], bf[n], acc[m][n], 0, 0, 0);
    __builtin_amdgcn_s_setprio(0);
    SBAR();
    // ---- phase 1: b(kk0,n4-7)
    #pragma unroll
    for (int n = 0; n < 4; n++) bf[n] = *(const bf16x8*)(ldsc + cb + boff0 + 8192 + n * 2048);
    SBAR();
    __builtin_amdgcn_s_setprio(1);
    #pragma unroll
    for (int m = 0; m < 4; m++)
      #pragma unroll
      for (int n = 0; n < 4; n++)
        acc[m][n + 4] = __builtin_amdgcn_mfma_f32_16x16x32_bf16(af[m], bf[n], acc[m][n + 4], 0, 0, 0);
    __builtin_amdgcn_s_setprio(0);
    SBAR();
    // ---- phase 2: a(kk1), b(kk1,n0-3)
    #pragma unroll
    for (int m = 0; m < 4; m++) af[m] = *(const bf16x8*)(ldsc + cb + aoff1 + m * 2048);
    #pragma unroll
    for (int n = 0; n < 4; n++) bf[n] = *(const bf16x8*)(ldsc + cb + boff1 + n * 2048);
    SBAR();
    __builtin_amdgcn_s_setprio(1);
    #pragma unroll
    for (int m = 0; m < 4; m++)
      #pragma unroll
      for (int n = 0; n < 4; n++)
        acc[m][n] = __builtin_amdgcn_mfma_f32_16x16x32_bf16(af[m], bf[n], acc[m][n], 0, 0, 0);
    __builtin_amdgcn_s_setprio(0);
    SBAR();
    // ---- phase 3: b(kk1,n4-7); drain; final barrier
    #pragma unroll
    for (int n = 0; n < 4; n++) bf[n] = *(const bf16x8*)(ldsc + cb + boff1 + 8192 + n * 2048);
    SBAR();
    __builtin_amdgcn_s_setprio(1);
    #pragma unroll
    for (int m = 0; m < 4; m++)
      #pragma unroll
      for (int n = 0; n < 4; n++)
        acc[m][n + 4] = __builtin_amdgcn_mfma_f32_16x16x32_bf16(af[m], bf[n], acc[m][n + 4], 0, 0, 0);
    __builtin_amdgcn_s_setprio(0);
    if (more) { VMCNT0(); SBAR(); }
  }

  #pragma unroll
  for (int m = 0; m < 4; m++) {
    const int rbase = wr * 64 + m * 16 + ((lane >> 4) << 2);
    #pragma unroll
    for (int n = 0; n < 8; n++) {
      const int col = n0 + wc * 128 + n * 16 + (lane & 15);
      #pragma unroll
      for (int j = 0; j < 4; j++) {
        const int r = rbase + j;
        if (r < d.nrows) {
          const int grow = d.row_start + r;
          float v = acc[m][n][j];
          if (d.e == NEXP) out[(size_t)(grow - 2 * T_TOK) * D_DIM + col] = v;
          else             eout[(size_t)grow * D_DIM + col] = v;
        }
      }
    }
  }
}

// ---------------- combine: out[t] += w0*eout[p0] + w1*eout[p1] ----------------
__global__ void k_combine(const float* __restrict__ eout, const int* __restrict__ pos,
                          const float* __restrict__ tk_w, float* __restrict__ out) {
  const int t = blockIdx.x;
  const int dc = threadIdx.x * 4;
  const int p0 = pos[t * 2], p1 = pos[t * 2 + 1];
  const float w0 = tk_w[t * 2], w1 = tk_w[t * 2 + 1];
  float* op = out + (size_t)t * D_DIM + dc;
  float4 o = *(float4*)op;
  float4 a = *(const float4*)(eout + (size_t)p0 * D_DIM + dc);
  float4 b = *(const float4*)(eout + (size_t)p1 * D_DIM + dc);
  o.x += w0 * a.x + w1 * b.x;
  o.y += w0 * a.y + w1 * b.y;
  o.z += w0 * a.z + w1 * b.z;
  o.w += w0 * a.w + w1 * b.w;
  *(float4*)op = o;
}

extern "C" void kernel_launch(void* const* d_in, const int* in_sizes, int n_in,
                              void* d_out, int out_size, void* d_ws, size_t ws_size,
                              hipStream_t stream) {
  const float* X    = (const float*)d_in[0];
  const float* Wr   = (const float*)d_in[1];
  const float* Wg_s = (const float*)d_in[2];
  const float* Wu_s = (const float*)d_in[3];
  const float* Wd_s = (const float*)d_in[4];
  const float* Wg   = (const float*)d_in[5];
  const float* Wu   = (const float*)d_in[6];
  const float* Wd   = (const float*)d_in[7];
  float* out = (float*)d_out;

  char* ws = (char*)d_ws;
  size_t o = 0;
  auto alloc = [&](size_t bytes) -> void* {
    void* p = ws + o;
    o += (bytes + 255) & ~(size_t)255;
    return p;
  };
  u16* Xb    = (u16*)alloc((size_t)T_TOK * D_DIM * 2);
  u16* WgTs  = (u16*)alloc((size_t)F_DIM * D_DIM * 2);
  u16* WuTs  = (u16*)alloc((size_t)F_DIM * D_DIM * 2);
  u16* WdTs  = (u16*)alloc((size_t)D_DIM * F_DIM * 2);
  u16* WgT   = (u16*)alloc((size_t)NEXP * F_DIM * D_DIM * 2);
  u16* WuT   = (u16*)alloc((size_t)NEXP * F_DIM * D_DIM * 2);
  u16* WdT   = (u16*)alloc((size_t)NEXP * D_DIM * F_DIM * 2);
  u16* h     = (u16*)alloc((size_t)(3 * T_TOK) * F_DIM * 2);
  float* eout= (float*)alloc((size_t)(2 * T_TOK) * D_DIM * 4);
  int* tk_idx= (int*)alloc((size_t)T_TOK * 2 * 4);
  float* tk_w= (float*)alloc((size_t)T_TOK * 2 * 4);
  int* pos   = (int*)alloc((size_t)T_TOK * 2 * 4);
  int* tok   = (int*)alloc((size_t)(3 * T_TOK) * 4);
  int* meta  = (int*)alloc(256);
  Desc* descs= (Desc*)alloc(NDESC * sizeof(Desc));
  if (o > ws_size) return;

  int* counts = meta, *offsets = meta + 8, *cursors = meta + 16;

  k_convert<<<(T_TOK * D_DIM / 8 + 255) / 256, 256, 0, stream>>>(X, Xb, T_TOK * D_DIM / 8, meta);
  k_tconv_all<<<dim3(16, 32, 27), 256, 0, stream>>>(Wg_s, Wu_s, Wd_s, Wg, Wu, Wd,
                                                    WgTs, WuTs, WdTs, WgT, WuT, WdT);
  k_router<<<T_TOK / 4, 256, 0, stream>>>(X, Wr, tk_idx, tk_w, counts);
  k_scan<<<1, 64, 0, stream>>>(counts, offsets, cursors, descs);
  k_scatter<<<T_TOK / 256, 256, 0, stream>>>(tk_idx, offsets, cursors, tok, pos);
  k_gemm1<<<dim3(16, NDESC), 512, 0, stream>>>(Xb, WgT, WuT, WgTs, WuTs, tok, descs, h);
  k_gemm2<<<dim3(4, NDESC), 512, 0, stream>>>(h, WdT, WdTs, descs, eout, out);
  k_combine<<<T_TOK, 256, 0, stream>>>(eout, pos, tk_w, out);
}